// Round 1
// baseline (62.980 us; speedup 1.0000x reference)
//
#include <hip/hip_runtime.h>
#include <math.h>

#define R_ 1.3f
#define NCOARSE 32
#define SAMPLES 383
#define BATCH 512
#define PAIRS 192                 // ceil(383/2)
#define STEPSZ 0.0203125f         // 2*1.3/32/2/2
#define INV_FINE_VLEN 24.615384615384617f  // 64 / 2.6

// Per-dim: for target fine-parity bit t in {0,1}, the summed weight W[t] and
// coarse index C[t]. Handles the clip-collapse case (both corners land in the
// same cell -> one parity gets w0+w1, the other 0) exactly like the reference
// sum over 8 corners.
__device__ __forceinline__ void dimwc(float p, float* W, int* C) {
    float post0 = fminf(fmaxf(floorf(p - 0.5f), 0.f), 63.f);
    float post1 = fminf(fmaxf(floorf(p + 0.5f), 0.f), 63.f);
    float w0 = 1.f - fabsf(p - (post0 + 0.5f));
    float w1 = 1.f - fabsf(p - (post1 + 0.5f));
    int i0 = (int)post0, i1 = (int)post1;
    int f0 = i0 & 1, f1 = i1 & 1;
    W[0] = (f0 == 0 ? w0 : 0.f) + (f1 == 0 ? w1 : 0.f);
    W[1] = (f0 == 1 ? w0 : 0.f) + (f1 == 1 ? w1 : 0.f);
    int c0 = i0 >> 1, c1 = i1 >> 1;
    C[0] = (f0 == 0) ? c0 : c1;
    C[1] = (f0 == 1) ? c0 : c1;
}

__global__ __launch_bounds__(256) void dp_sample(
    const float* __restrict__ rays_o, const float* __restrict__ rays_d,
    const float* __restrict__ grid, const float* __restrict__ atoms,
    float* __restrict__ out_alpha, float* __restrict__ ws_sig,
    float* __restrict__ out_loss)
{
    // atoms -> LDS, [f][a][32] (pad 28->32 for aligned b128 reads)
    __shared__ float atl[8 * 32 * 32];
    for (int i = threadIdx.x; i < 8 * 32 * 28; i += 256) {
        int f = i / 896, r = i - f * 896;
        int a = r / 28, d = r - a * 28;
        atl[(f * 32 + a) * 32 + d] = atoms[i];
    }
    __syncthreads();

    const int gid = blockIdx.x * 256 + threadIdx.x;   // 0 .. 98303
    if (gid == 0) out_loss[0] = 0.f;
    const int b = gid / PAIRS;
    const int q = gid - b * PAIRS;
    const int s0 = 2 * q;
    const bool vB = (s0 + 1) < SAMPLES;

    const float ox = rays_o[3 * b + 0], oy = rays_o[3 * b + 1], oz = rays_o[3 * b + 2];
    const float dx = rays_d[3 * b + 0], dy = rays_d[3 * b + 1], dz = rays_d[3 * b + 2];

    const float start = fmaxf(fmaxf(
        fminf((R_ - ox) / dx, (-R_ - ox) / dx),
        fminf((R_ - oy) / dy, (-R_ - oy) / dy)),
        fminf((R_ - oz) / dz, (-R_ - oz) / dz));
    const float lend = sqrtf(dx * dx + dy * dy + dz * dz);
    const float dist = STEPSZ * lend;

    const float tA = start + s0 * STEPSZ;
    const float tB = start + (s0 + 1) * STEPSZ;
    const float pAx = ox + tA * dx, pAy = oy + tA * dy, pAz = oz + tA * dz;
    const float pBx = ox + tB * dx, pBy = oy + tB * dy, pBz = oz + tB * dz;
    const bool mA = (pAx > -R_ && pAx < R_ && pAy > -R_ && pAy < R_ && pAz > -R_ && pAz < R_);
    const bool mB = vB && (pBx > -R_ && pBx < R_ && pBy > -R_ && pBy < R_ && pBz > -R_ && pBz < R_);

    float accA[28], accB[28];
#pragma unroll
    for (int i = 0; i < 28; ++i) { accA[i] = 0.f; accB[i] = 0.f; }

    if (mA || mB) {
        // sanitize coords for masked/invalid sample so no NaN/inf leaks via 0*x
        const float gAx = mA ? (pAx + R_) * INV_FINE_VLEN : 32.f;
        const float gAy = mA ? (pAy + R_) * INV_FINE_VLEN : 32.f;
        const float gAz = mA ? (pAz + R_) * INV_FINE_VLEN : 32.f;
        const float gBx = mB ? (pBx + R_) * INV_FINE_VLEN : 32.f;
        const float gBy = mB ? (pBy + R_) * INV_FINE_VLEN : 32.f;
        const float gBz = mB ? (pBz + R_) * INV_FINE_VLEN : 32.f;

        float WA0[2], WA1[2], WA2[2], WB0[2], WB1[2], WB2[2];
        int   CA0[2], CA1[2], CA2[2], CB0[2], CB1[2], CB2[2];
        dimwc(gAx, WA0, CA0); dimwc(gAy, WA1, CA1); dimwc(gAz, WA2, CA2);
        dimwc(gBx, WB0, CB0); dimwc(gBy, WB1, CB1); dimwc(gBz, WB2, CB2);
        const float mskA = mA ? 1.f : 0.f;
        const float mskB = mB ? 1.f : 0.f;

#pragma unroll
        for (int f = 0; f < 8; ++f) {
            const int fx = (f >> 2) & 1, fy = (f >> 1) & 1, fz = f & 1;
            const float wA = mskA * WA0[fx] * WA1[fy] * WA2[fz];
            const float wB = mskB * WB0[fx] * WB1[fy] * WB2[fz];
            const int cfA = (CA0[fx] * NCOARSE + CA1[fy]) * NCOARSE + CA2[fz];
            const int cfB = (CB0[fx] * NCOARSE + CB1[fy]) * NCOARSE + CB2[fz];
            const float4* gA4 = (const float4*)(grid + cfA * 32);
            const float4* gB4 = (const float4*)(grid + cfB * 32);
            const float4* af4 = (const float4*)(atl + f * 1024);
            for (int a4 = 0; a4 < 8; ++a4) {
                const float4 gvA = gA4[a4];
                const float4 gvB = gB4[a4];
#pragma unroll
                for (int j = 0; j < 4; ++j) {
                    const float ga = (j == 0) ? gvA.x : (j == 1) ? gvA.y : (j == 2) ? gvA.z : gvA.w;
                    const float gb = (j == 0) ? gvB.x : (j == 1) ? gvB.y : (j == 2) ? gvB.z : gvB.w;
                    const float wgA = wA * ga;
                    const float wgB = wB * gb;
                    const float4* ar = af4 + (a4 * 4 + j) * 8;
#pragma unroll
                    for (int d4 = 0; d4 < 7; ++d4) {
                        const float4 av = ar[d4];  // wave-uniform -> LDS broadcast
                        accA[4 * d4 + 0] += wgA * av.x;
                        accA[4 * d4 + 1] += wgA * av.y;
                        accA[4 * d4 + 2] += wgA * av.z;
                        accA[4 * d4 + 3] += wgA * av.w;
                        accB[4 * d4 + 0] += wgB * av.x;
                        accB[4 * d4 + 1] += wgB * av.y;
                        accB[4 * d4 + 2] += wgB * av.z;
                        accB[4 * d4 + 3] += wgB * av.w;
                    }
                }
            }
        }
    }

    // SH basis (degree 2) on normalized dir
    const float inv = 1.f / lend;
    const float nx = dx * inv, ny = dy * inv, nz = dz * inv;
    float sh[9];
    sh[0] = 0.28209479177387814f;
    sh[1] = -0.48860251190291987f * ny;
    sh[2] = 0.48860251190291987f * nz;
    sh[3] = -0.48860251190291987f * nx;
    sh[4] = 1.0925484305920792f * nx * ny;
    sh[5] = -1.0925484305920792f * ny * nz;
    sh[6] = 0.31539156525252005f * (2.f * nz * nz - nx * nx - ny * ny);
    sh[7] = -1.0925484305920792f * nx * nz;
    sh[8] = 0.5462742152960396f * (nx * nx - ny * ny);

    // sample A epilogue
    {
        const float sigma = fmaxf(accA[27], 0.f);
        const float alpha = 1.f - expf(-sigma * dist);   // == 0 when masked (acc==0)
        out_alpha[b * SAMPLES + s0] = alpha;
        float* sp = ws_sig + (b * SAMPLES + s0) * 3;
#pragma unroll
        for (int c = 0; c < 3; ++c) {
            float r = 0.f;
#pragma unroll
            for (int k = 0; k < 9; ++k) r += sh[k] * accA[c * 9 + k];
            sp[c] = 1.f / (1.f + expf(-r));
        }
    }
    // sample B epilogue
    if (vB) {
        const float sigma = fmaxf(accB[27], 0.f);
        const float alpha = 1.f - expf(-sigma * dist);
        out_alpha[b * SAMPLES + s0 + 1] = alpha;
        float* sp = ws_sig + (b * SAMPLES + s0 + 1) * 3;
#pragma unroll
        for (int c = 0; c < 3; ++c) {
            float r = 0.f;
#pragma unroll
            for (int k = 0; k < 9; ++k) r += sh[k] * accB[c * 9 + k];
            sp[c] = 1.f / (1.f + expf(-r));
        }
    }
}

// One wave (64 lanes) per ray: ordered cumprod scan + reductions.
__global__ __launch_bounds__(64) void dp_composite(
    const float* __restrict__ rays_o, const float* __restrict__ rays_d,
    const float* __restrict__ alpha_in, const float* __restrict__ ws_sig,
    float* __restrict__ rgb_out, float* __restrict__ depth_out)
{
    const int b = blockIdx.x;
    const int l = threadIdx.x;
    const float ox = rays_o[3 * b + 0], oy = rays_o[3 * b + 1], oz = rays_o[3 * b + 2];
    const float dx = rays_d[3 * b + 0], dy = rays_d[3 * b + 1], dz = rays_d[3 * b + 2];
    const float start = fmaxf(fmaxf(
        fminf((R_ - ox) / dx, (-R_ - ox) / dx),
        fminf((R_ - oy) / dy, (-R_ - oy) / dy)),
        fminf((R_ - oz) / dz, (-R_ - oz) / dz));

    float Tacc = 1.f;
    float r0 = 0.f, r1 = 0.f, r2 = 0.f, sd = 0.f, sa = 0.f;
    for (int j = 0; j < 6; ++j) {
        const int s = j * 64 + l;
        const bool v = s < SAMPLES;
        const float a = v ? alpha_in[b * SAMPLES + s] : 0.f;
        float incl = v ? (1.f - a + 1e-10f) : 1.f;
#pragma unroll
        for (int off = 1; off < 64; off <<= 1) {
            const float t = __shfl_up(incl, off, 64);
            if (l >= off) incl *= t;
        }
        float excl = __shfl_up(incl, 1, 64);
        if (l == 0) excl = 1.f;
        const float T = Tacc * excl;
        const float al = a * T;
        if (v) {
            const float* sp = ws_sig + (b * SAMPLES + s) * 3;
            r0 += al * sp[0];
            r1 += al * sp[1];
            r2 += al * sp[2];
            sd += al * (start + s * STEPSZ);
            sa += al;
        }
        Tacc *= __shfl(incl, 63, 64);
    }
#pragma unroll
    for (int m = 32; m > 0; m >>= 1) {
        r0 += __shfl_xor(r0, m, 64);
        r1 += __shfl_xor(r1, m, 64);
        r2 += __shfl_xor(r2, m, 64);
        sd += __shfl_xor(sd, m, 64);
        sa += __shfl_xor(sa, m, 64);
    }
    if (l == 0) {
        const float base = 1.f - sa;
        rgb_out[b * 3 + 0] = r0 + base;
        rgb_out[b * 3 + 1] = r1 + base;
        rgb_out[b * 3 + 2] = r2 + base;
        depth_out[b] = sd;
    }
}

extern "C" void kernel_launch(void* const* d_in, const int* in_sizes, int n_in,
                              void* d_out, int out_size, void* d_ws, size_t ws_size,
                              hipStream_t stream) {
    const float* rays_o = (const float*)d_in[0];
    const float* rays_d = (const float*)d_in[1];
    const float* grid   = (const float*)d_in[2];
    const float* atoms  = (const float*)d_in[3];
    float* out   = (float*)d_out;
    float* rgb   = out;                                   // [512,3]
    float* alpha = out + BATCH * 3;                       // [512,383]
    float* depth = out + BATCH * 3 + BATCH * SAMPLES;     // [512]
    float* loss  = out + BATCH * 3 + BATCH * SAMPLES + BATCH;  // scalar
    float* sig   = (float*)d_ws;                          // [512*383*3]

    dp_sample<<<dim3(BATCH * PAIRS / 256), dim3(256), 0, stream>>>(
        rays_o, rays_d, grid, atoms, alpha, sig, loss);
    dp_composite<<<dim3(BATCH), dim3(64), 0, stream>>>(
        rays_o, rays_d, alpha, sig, rgb, depth);
}

// Round 2
// 35.517 us; speedup vs baseline: 1.7732x; 1.7732x over previous
//
#include <hip/hip_runtime.h>
#include <math.h>

#define R_ 1.3f
#define NCOARSE 32
#define SAMPLES 383
#define BATCH 512
#define STEPSZ 0.0203125f                  // 2*1.3/32/2/2
#define INV_FINE_VLEN 24.615384615384617f  // 64 / 2.6

using f32x4 = __attribute__((ext_vector_type(4))) float;
using s16x8 = __attribute__((ext_vector_type(8))) short;
using u32x4 = __attribute__((ext_vector_type(4))) unsigned int;

// f32 pair -> packed bf16 (RNE)
__device__ __forceinline__ unsigned int packbf2(float lo, float hi) {
    unsigned int a = __builtin_bit_cast(unsigned int, lo);
    unsigned int b = __builtin_bit_cast(unsigned int, hi);
    a = (a + 0x7fffu + ((a >> 16) & 1u)) >> 16;
    b = (b + 0x7fffu + ((b >> 16) & 1u)) >> 16;
    return (a & 0xffffu) | (b << 16);
}

// Per-dim: summed weight W[t] and coarse index C[t] for fine-parity t.
__device__ __forceinline__ void dimwc(float p, float* W, int* C) {
    float post0 = fminf(fmaxf(floorf(p - 0.5f), 0.f), 63.f);
    float post1 = fminf(fmaxf(floorf(p + 0.5f), 0.f), 63.f);
    float w0 = 1.f - fabsf(p - (post0 + 0.5f));
    float w1 = 1.f - fabsf(p - (post1 + 0.5f));
    int i0 = (int)post0, i1 = (int)post1;
    int f0 = i0 & 1, f1 = i1 & 1;
    W[0] = (f0 == 0 ? w0 : 0.f) + (f1 == 0 ? w1 : 0.f);
    W[1] = (f0 == 1 ? w0 : 0.f) + (f1 == 1 ? w1 : 0.f);
    int c0 = i0 >> 1, c1 = i1 >> 1;
    C[0] = (f0 == 0) ? c0 : c1;
    C[1] = (f0 == 1) ? c0 : c1;
}

// ---- prep: build B fragments (atoms in MFMA-B layout, bf16) + zero loss ----
// Bws layout: [kb(8)][nt(2)][lane(64)] of u32x4  (8 bf16 per lane per frag)
// B[k][d] = atoms[f=kb][a=k%32][d], frag: lane l holds col d=nt*16+(l&15),
// k = kb*32 + 8*(l>>4) + e, e=0..7.
__global__ __launch_bounds__(256) void dp_prep(
    const float* __restrict__ atoms, unsigned int* __restrict__ Bws,
    float* __restrict__ out_loss)
{
    const int t = threadIdx.x;
    if (t == 0) out_loss[0] = 0.f;
#pragma unroll
    for (int i = 0; i < 4; ++i) {
        const int slot = t * 4 + i;        // 0..1023
        const int l  = slot & 63;
        const int nt = (slot >> 6) & 1;
        const int kb = slot >> 7;
        const int a0 = (l >> 4) * 8;
        const int d  = nt * 16 + (l & 15);
        u32x4 o;
#pragma unroll
        for (int e2 = 0; e2 < 4; ++e2) {
            float lo = 0.f, hi = 0.f;
            if (d < 28) {
                lo = atoms[(kb * 32 + a0 + 2 * e2) * 28 + d];
                hi = atoms[(kb * 32 + a0 + 2 * e2 + 1) * 28 + d];
            }
            o[e2] = packbf2(lo, hi);
        }
        ((u32x4*)Bws)[slot] = o;
    }
}

// ---- main: per-wave 16-sample tiles, MFMA contraction ----
__global__ __launch_bounds__(256) void dp_mfma(
    const float* __restrict__ rays_o, const float* __restrict__ rays_d,
    const float* __restrict__ grid, const unsigned int* __restrict__ Bws,
    float* __restrict__ out_alpha, float* __restrict__ ws_sig)
{
    __shared__ unsigned int lds[4][2048];      // 8 KB per wave
    const int tid = threadIdx.x;
    const int wid = tid >> 6, l = tid & 63;
    unsigned int* W = lds[wid];
    const int sl = l & 15;    // sample slot in tile
    const int fp = l >> 4;    // corner-pair id

    // B fragments -> registers (held across tiles)
    s16x8 bfrag[8][2];
    const u32x4* bsrc = (const u32x4*)Bws;
#pragma unroll
    for (int kb = 0; kb < 8; ++kb)
#pragma unroll
        for (int nt = 0; nt < 2; ++nt)
            bfrag[kb][nt] = __builtin_bit_cast(s16x8, bsrc[(kb * 2 + nt) * 64 + l]);

    for (int t = 0; t < 4; ++t) {
        const int gbase = blockIdx.x * 256 + wid * 64 + t * 16;
        const int g = gbase + sl;          // flat sample id, < 196096
        const int b = g / SAMPLES;
        const int s = g - b * SAMPLES;

        const float ox = rays_o[3 * b], oy = rays_o[3 * b + 1], oz = rays_o[3 * b + 2];
        const float dx = rays_d[3 * b], dy = rays_d[3 * b + 1], dz = rays_d[3 * b + 2];
        const float start = fmaxf(fmaxf(
            fminf((R_ - ox) / dx, (-R_ - ox) / dx),
            fminf((R_ - oy) / dy, (-R_ - oy) / dy)),
            fminf((R_ - oz) / dz, (-R_ - oz) / dz));
        const float tt = start + s * STEPSZ;
        const float px = ox + tt * dx, py = oy + tt * dy, pz = oz + tt * dz;
        const bool m = (px > -R_ && px < R_ && py > -R_ && py < R_ && pz > -R_ && pz < R_);

        const unsigned long long bal = __ballot(m);
        if (bal == 0ull) {                 // whole tile outside: zero outputs
            if (l < 16) {
                out_alpha[g] = 0.f;
                ws_sig[3 * g + 0] = 0.f;
                ws_sig[3 * g + 1] = 0.f;
                ws_sig[3 * g + 2] = 0.f;
            }
            continue;
        }

        // ---- build A fragments: G[s][k] = w_f * grid[c_f, a], k=f*32+a ----
        float W0[2], W1[2], W2[2];
        int C0[2], C1[2], C2[2];
        dimwc((px + R_) * INV_FINE_VLEN, W0, C0);
        dimwc((py + R_) * INV_FINE_VLEN, W1, C1);
        dimwc((pz + R_) * INV_FINE_VLEN, W2, C2);
        const float msk = m ? 1.f : 0.f;
#pragma unroll
        for (int i = 0; i < 2; ++i) {
            const int f = 2 * fp + i;
            const int fx = (f >> 2) & 1, fy = (f >> 1) & 1, fz = f & 1;
            const float wf = msk * W0[fx] * W1[fy] * W2[fz];
            const int cf = (C0[fx] * NCOARSE + C1[fy]) * NCOARSE + C2[fz];
            const f32x4* gr = (const f32x4*)(grid + cf * 32);
#pragma unroll
            for (int g4 = 0; g4 < 4; ++g4) {
                const f32x4 v0 = gr[2 * g4];
                const f32x4 v1 = gr[2 * g4 + 1];
                u32x4 o;
                o.x = packbf2(wf * v0.x, wf * v0.y);
                o.y = packbf2(wf * v0.z, wf * v0.w);
                o.z = packbf2(wf * v1.x, wf * v1.y);
                o.w = packbf2(wf * v1.z, wf * v1.w);
                // A-frag store: lane' = sl + 16*(a/8), kb = f
                ((u32x4*)W)[f * 64 + 16 * g4 + sl] = o;
            }
        }

        // ---- MFMA: D[s][d] = sum_k G[s,k] * B[k,d] ----
        f32x4 acc0 = {0.f, 0.f, 0.f, 0.f};
        f32x4 acc1 = {0.f, 0.f, 0.f, 0.f};
#pragma unroll
        for (int kb = 0; kb < 8; ++kb) {
            const s16x8 af = __builtin_bit_cast(s16x8, ((u32x4*)W)[kb * 64 + l]);
            acc0 = __builtin_amdgcn_mfma_f32_16x16x32_bf16(af, bfrag[kb][0], acc0, 0, 0, 0);
            acc1 = __builtin_amdgcn_mfma_f32_16x16x32_bf16(af, bfrag[kb][1], acc1, 0, 0, 0);
        }

        // ---- epilogue: D to LDS (row=sample, col=d, stride 32) ----
        float* Dbuf = (float*)W;
#pragma unroll
        for (int r = 0; r < 4; ++r) {
            Dbuf[(4 * fp + r) * 32 + sl]      = acc0[r];
            Dbuf[(4 * fp + r) * 32 + sl + 16] = acc1[r];
        }

        const int s2 = l >> 2, c = l & 3;  // lane -> (sample, channel)
        const int g2 = gbase + s2;
        const int b2 = g2 / SAMPLES;
        const int ss2 = g2 - b2 * SAMPLES;
        const float d2x = rays_d[3 * b2], d2y = rays_d[3 * b2 + 1], d2z = rays_d[3 * b2 + 2];
        const float lend2 = sqrtf(d2x * d2x + d2y * d2y + d2z * d2z);
        (void)ss2;
        if (c == 3) {
            const float sigma = fmaxf(Dbuf[s2 * 32 + 27], 0.f);
            out_alpha[g2] = 1.f - expf(-sigma * STEPSZ * lend2);
        } else {
            const float inv = 1.f / lend2;
            const float nx = d2x * inv, ny = d2y * inv, nz = d2z * inv;
            float sh[9];
            sh[0] = 0.28209479177387814f;
            sh[1] = -0.48860251190291987f * ny;
            sh[2] = 0.48860251190291987f * nz;
            sh[3] = -0.48860251190291987f * nx;
            sh[4] = 1.0925484305920792f * nx * ny;
            sh[5] = -1.0925484305920792f * ny * nz;
            sh[6] = 0.31539156525252005f * (2.f * nz * nz - nx * nx - ny * ny);
            sh[7] = -1.0925484305920792f * nx * nz;
            sh[8] = 0.5462742152960396f * (nx * nx - ny * ny);
            float r_ = 0.f;
#pragma unroll
            for (int k = 0; k < 9; ++k) r_ += sh[k] * Dbuf[s2 * 32 + c * 9 + k];
            ws_sig[3 * g2 + c] = 1.f / (1.f + expf(-r_));
        }
    }
}

// ---- compositing: one wave per ray, ordered cumprod scan ----
__global__ __launch_bounds__(64) void dp_composite(
    const float* __restrict__ rays_o, const float* __restrict__ rays_d,
    const float* __restrict__ alpha_in, const float* __restrict__ ws_sig,
    float* __restrict__ rgb_out, float* __restrict__ depth_out)
{
    const int b = blockIdx.x;
    const int l = threadIdx.x;
    const float ox = rays_o[3 * b], oy = rays_o[3 * b + 1], oz = rays_o[3 * b + 2];
    const float dx = rays_d[3 * b], dy = rays_d[3 * b + 1], dz = rays_d[3 * b + 2];
    const float start = fmaxf(fmaxf(
        fminf((R_ - ox) / dx, (-R_ - ox) / dx),
        fminf((R_ - oy) / dy, (-R_ - oy) / dy)),
        fminf((R_ - oz) / dz, (-R_ - oz) / dz));

    float Tacc = 1.f;
    float r0 = 0.f, r1 = 0.f, r2 = 0.f, sd = 0.f, sa = 0.f;
    for (int j = 0; j < 6; ++j) {
        const int s = j * 64 + l;
        const bool v = s < SAMPLES;
        const float a = v ? alpha_in[b * SAMPLES + s] : 0.f;
        float incl = v ? (1.f - a + 1e-10f) : 1.f;
#pragma unroll
        for (int off = 1; off < 64; off <<= 1) {
            const float t = __shfl_up(incl, off, 64);
            if (l >= off) incl *= t;
        }
        float excl = __shfl_up(incl, 1, 64);
        if (l == 0) excl = 1.f;
        const float T = Tacc * excl;
        const float al = a * T;
        if (v) {
            const float* sp = ws_sig + (b * SAMPLES + s) * 3;
            r0 += al * sp[0];
            r1 += al * sp[1];
            r2 += al * sp[2];
            sd += al * (start + s * STEPSZ);
            sa += al;
        }
        Tacc *= __shfl(incl, 63, 64);
    }
#pragma unroll
    for (int m = 32; m > 0; m >>= 1) {
        r0 += __shfl_xor(r0, m, 64);
        r1 += __shfl_xor(r1, m, 64);
        r2 += __shfl_xor(r2, m, 64);
        sd += __shfl_xor(sd, m, 64);
        sa += __shfl_xor(sa, m, 64);
    }
    if (l == 0) {
        const float base = 1.f - sa;
        rgb_out[b * 3 + 0] = r0 + base;
        rgb_out[b * 3 + 1] = r1 + base;
        rgb_out[b * 3 + 2] = r2 + base;
        depth_out[b] = sd;
    }
}

extern "C" void kernel_launch(void* const* d_in, const int* in_sizes, int n_in,
                              void* d_out, int out_size, void* d_ws, size_t ws_size,
                              hipStream_t stream) {
    const float* rays_o = (const float*)d_in[0];
    const float* rays_d = (const float*)d_in[1];
    const float* grid   = (const float*)d_in[2];
    const float* atoms  = (const float*)d_in[3];
    float* out   = (float*)d_out;
    float* rgb   = out;                                        // [512,3]
    float* alpha = out + BATCH * 3;                            // [512,383]
    float* depth = out + BATCH * 3 + BATCH * SAMPLES;          // [512]
    float* loss  = out + BATCH * 3 + BATCH * SAMPLES + BATCH;  // scalar

    unsigned int* Bws = (unsigned int*)d_ws;                   // 16 KB (4096 u32)
    float* sig = (float*)d_ws + 4096;                          // [512*383*3] f32

    dp_prep<<<dim3(1), dim3(256), 0, stream>>>(atoms, Bws, loss);
    dp_mfma<<<dim3((BATCH * SAMPLES) / 256), dim3(256), 0, stream>>>(
        rays_o, rays_d, grid, Bws, alpha, sig);
    dp_composite<<<dim3(BATCH), dim3(64), 0, stream>>>(
        rays_o, rays_d, alpha, sig, rgb, depth);
}

// Round 3
// 20.449 us; speedup vs baseline: 3.0799x; 1.7369x over previous
//
#include <hip/hip_runtime.h>
#include <math.h>

#define R_ 1.3f
#define NCOARSE 32
#define SAMPLES 383
#define BATCH 512
#define STEPSZ 0.0203125f                  // 2*1.3/32/2/2
#define INV_FINE_VLEN 24.615384615384617f  // 64 / 2.6

using f32x4 = __attribute__((ext_vector_type(4))) float;
using s16x8 = __attribute__((ext_vector_type(8))) short;
using u32x4 = __attribute__((ext_vector_type(4))) unsigned int;

// f32 pair -> packed bf16 (RNE)
__device__ __forceinline__ unsigned int packbf2(float lo, float hi) {
    unsigned int a = __builtin_bit_cast(unsigned int, lo);
    unsigned int b = __builtin_bit_cast(unsigned int, hi);
    a = (a + 0x7fffu + ((a >> 16) & 1u)) >> 16;
    b = (b + 0x7fffu + ((b >> 16) & 1u)) >> 16;
    return (a & 0xffffu) | (b << 16);
}

// Per-dim: summed weight W[t] and coarse index C[t] for fine-parity t.
__device__ __forceinline__ void dimwc(float p, float* W, int* C) {
    float post0 = fminf(fmaxf(floorf(p - 0.5f), 0.f), 63.f);
    float post1 = fminf(fmaxf(floorf(p + 0.5f), 0.f), 63.f);
    float w0 = 1.f - fabsf(p - (post0 + 0.5f));
    float w1 = 1.f - fabsf(p - (post1 + 0.5f));
    int i0 = (int)post0, i1 = (int)post1;
    int f0 = i0 & 1, f1 = i1 & 1;
    W[0] = (f0 == 0 ? w0 : 0.f) + (f1 == 0 ? w1 : 0.f);
    W[1] = (f0 == 1 ? w0 : 0.f) + (f1 == 1 ? w1 : 0.f);
    int c0 = i0 >> 1, c1 = i1 >> 1;
    C[0] = (f0 == 0) ? c0 : c1;
    C[1] = (f0 == 1) ? c0 : c1;
}

// One ray per block. 4 waves; wave w handles tiles {w, w+4, ..., w+20}
// (24 tiles x 16 samples = 384 slots covering s = 0..382 + 1 pad).
__global__ __launch_bounds__(256) void dp_fused(
    const float* __restrict__ rays_o, const float* __restrict__ rays_d,
    const float* __restrict__ grid, const float* __restrict__ atoms,
    float* __restrict__ out_rgb, float* __restrict__ out_alpha,
    float* __restrict__ out_depth, float* __restrict__ out_loss)
{
    __shared__ unsigned int Abuf[4][2048];   // 8 KB per wave: A-frag / D staging
    __shared__ float alpha_l[384];
    __shared__ float sig_l[384][3];

    const int b = blockIdx.x;
    const int tid = threadIdx.x;
    const int wid = tid >> 6, l = tid & 63;
    const int sl = l & 15, fp = l >> 4;
    if (b == 0 && tid == 0) out_loss[0] = 0.f;

    // ---- B fragments from atoms (28 KB, L2-resident), same layout as verified ----
    // lane l, frag[kb][nt]: col d = nt*16+(l&15), k = kb*32 + (l>>4)*8 + e
    s16x8 bfrag[8][2];
    {
        const int a0 = (l >> 4) * 8;
#pragma unroll
        for (int kb = 0; kb < 8; ++kb)
#pragma unroll
            for (int nt = 0; nt < 2; ++nt) {
                const int d = nt * 16 + (l & 15);
                u32x4 o;
#pragma unroll
                for (int e2 = 0; e2 < 4; ++e2) {
                    float lo = 0.f, hi = 0.f;
                    if (d < 28) {
                        lo = atoms[(kb * 32 + a0 + 2 * e2) * 28 + d];
                        hi = atoms[(kb * 32 + a0 + 2 * e2 + 1) * 28 + d];
                    }
                    o[e2] = packbf2(lo, hi);
                }
                bfrag[kb][nt] = __builtin_bit_cast(s16x8, o);
            }
    }

    // ---- ray setup (block-uniform -> SGPRs) ----
    const float ox = rays_o[3 * b], oy = rays_o[3 * b + 1], oz = rays_o[3 * b + 2];
    const float dx = rays_d[3 * b], dy = rays_d[3 * b + 1], dz = rays_d[3 * b + 2];
    const float start = fmaxf(fmaxf(
        fminf((R_ - ox) / dx, (-R_ - ox) / dx),
        fminf((R_ - oy) / dy, (-R_ - oy) / dy)),
        fminf((R_ - oz) / dz, (-R_ - oz) / dz));
    const float lend = sqrtf(dx * dx + dy * dy + dz * dz);
    const float dist = STEPSZ * lend;
    const float inv = 1.f / lend;
    const float nx = dx * inv, ny = dy * inv, nz = dz * inv;
    float sh[9];
    sh[0] = 0.28209479177387814f;
    sh[1] = -0.48860251190291987f * ny;
    sh[2] = 0.48860251190291987f * nz;
    sh[3] = -0.48860251190291987f * nx;
    sh[4] = 1.0925484305920792f * nx * ny;
    sh[5] = -1.0925484305920792f * ny * nz;
    sh[6] = 0.31539156525252005f * (2.f * nz * nz - nx * nx - ny * ny);
    sh[7] = -1.0925484305920792f * nx * nz;
    sh[8] = 0.5462742152960396f * (nx * nx - ny * ny);

    unsigned int* W = Abuf[wid];
    float* Dbuf = (float*)W;

    // ---- sample phase: 6 tiles per wave, interleaved for balance ----
    for (int j = 0; j < 6; ++j) {
        const int t = 4 * j + wid;
        const int s = t * 16 + sl;
        const float tt = start + s * STEPSZ;
        const float px = ox + tt * dx, py = oy + tt * dy, pz = oz + tt * dz;
        const bool m = (s < SAMPLES) &&
                       (px > -R_ && px < R_ && py > -R_ && py < R_ && pz > -R_ && pz < R_);

        if (__ballot(m) == 0ull) {           // whole tile outside
            if (l < 16) {
                const int so = t * 16 + l;
                if (so < SAMPLES) out_alpha[b * SAMPLES + so] = 0.f;
                alpha_l[so] = 0.f;
                sig_l[so][0] = 0.f; sig_l[so][1] = 0.f; sig_l[so][2] = 0.f;
            }
            continue;
        }

        // A fragments: G[s][k] = w_f * grid[c_f, a], k = f*32 + a
        float W0[2], W1[2], W2[2];
        int C0[2], C1[2], C2[2];
        dimwc((px + R_) * INV_FINE_VLEN, W0, C0);
        dimwc((py + R_) * INV_FINE_VLEN, W1, C1);
        dimwc((pz + R_) * INV_FINE_VLEN, W2, C2);
        const float msk = m ? 1.f : 0.f;
#pragma unroll
        for (int i = 0; i < 2; ++i) {
            const int f = 2 * fp + i;
            const int fx = (f >> 2) & 1, fy = (f >> 1) & 1, fz = f & 1;
            const float wf = msk * W0[fx] * W1[fy] * W2[fz];
            const int cf = (C0[fx] * NCOARSE + C1[fy]) * NCOARSE + C2[fz];
            const f32x4* gr = (const f32x4*)(grid + cf * 32);
#pragma unroll
            for (int g4 = 0; g4 < 4; ++g4) {
                const f32x4 v0 = gr[2 * g4];
                const f32x4 v1 = gr[2 * g4 + 1];
                u32x4 o;
                o.x = packbf2(wf * v0.x, wf * v0.y);
                o.y = packbf2(wf * v0.z, wf * v0.w);
                o.z = packbf2(wf * v1.x, wf * v1.y);
                o.w = packbf2(wf * v1.z, wf * v1.w);
                ((u32x4*)W)[f * 64 + 16 * g4 + sl] = o;
            }
        }

        f32x4 acc0 = {0.f, 0.f, 0.f, 0.f};
        f32x4 acc1 = {0.f, 0.f, 0.f, 0.f};
#pragma unroll
        for (int kb = 0; kb < 8; ++kb) {
            const s16x8 af = __builtin_bit_cast(s16x8, ((u32x4*)W)[kb * 64 + l]);
            acc0 = __builtin_amdgcn_mfma_f32_16x16x32_bf16(af, bfrag[kb][0], acc0, 0, 0, 0);
            acc1 = __builtin_amdgcn_mfma_f32_16x16x32_bf16(af, bfrag[kb][1], acc1, 0, 0, 0);
        }

        // D -> LDS (row = sample slot, stride 32)
#pragma unroll
        for (int r = 0; r < 4; ++r) {
            Dbuf[(4 * fp + r) * 32 + sl]      = acc0[r];
            Dbuf[(4 * fp + r) * 32 + sl + 16] = acc1[r];
        }

        // epilogue: lane -> (sample s2, channel c)
        const int s2 = l >> 2, c = l & 3;
        const int so = t * 16 + s2;
        if (c == 3) {
            const float sigma = fmaxf(Dbuf[s2 * 32 + 27], 0.f);
            const float a = 1.f - expf(-sigma * dist);
            alpha_l[so] = a;
            if (so < SAMPLES) out_alpha[b * SAMPLES + so] = a;
        } else {
            float r_ = 0.f;
#pragma unroll
            for (int k = 0; k < 9; ++k) r_ += sh[k] * Dbuf[s2 * 32 + c * 9 + k];
            sig_l[so][c] = 1.f / (1.f + expf(-r_));
        }
    }

    __syncthreads();

    // ---- compositing scan (wave 0 only) ----
    if (wid == 0) {
        float Tacc = 1.f;
        float r0 = 0.f, r1 = 0.f, r2 = 0.f, sd = 0.f, sa = 0.f;
        for (int j = 0; j < 6; ++j) {
            const int s = j * 64 + l;
            const bool v = s < SAMPLES;
            const float a = v ? alpha_l[s] : 0.f;
            float incl = v ? (1.f - a + 1e-10f) : 1.f;
#pragma unroll
            for (int off = 1; off < 64; off <<= 1) {
                const float tm = __shfl_up(incl, off, 64);
                if (l >= off) incl *= tm;
            }
            float excl = __shfl_up(incl, 1, 64);
            if (l == 0) excl = 1.f;
            const float T = Tacc * excl;
            const float al = a * T;
            if (v) {
                r0 += al * sig_l[s][0];
                r1 += al * sig_l[s][1];
                r2 += al * sig_l[s][2];
                sd += al * (start + s * STEPSZ);
                sa += al;
            }
            Tacc *= __shfl(incl, 63, 64);
        }
#pragma unroll
        for (int m = 32; m > 0; m >>= 1) {
            r0 += __shfl_xor(r0, m, 64);
            r1 += __shfl_xor(r1, m, 64);
            r2 += __shfl_xor(r2, m, 64);
            sd += __shfl_xor(sd, m, 64);
            sa += __shfl_xor(sa, m, 64);
        }
        if (l == 0) {
            const float base = 1.f - sa;
            out_rgb[b * 3 + 0] = r0 + base;
            out_rgb[b * 3 + 1] = r1 + base;
            out_rgb[b * 3 + 2] = r2 + base;
            out_depth[b] = sd;
        }
    }
}

extern "C" void kernel_launch(void* const* d_in, const int* in_sizes, int n_in,
                              void* d_out, int out_size, void* d_ws, size_t ws_size,
                              hipStream_t stream) {
    const float* rays_o = (const float*)d_in[0];
    const float* rays_d = (const float*)d_in[1];
    const float* grid   = (const float*)d_in[2];
    const float* atoms  = (const float*)d_in[3];
    float* out   = (float*)d_out;
    float* rgb   = out;                                        // [512,3]
    float* alpha = out + BATCH * 3;                            // [512,383]
    float* depth = out + BATCH * 3 + BATCH * SAMPLES;          // [512]
    float* loss  = out + BATCH * 3 + BATCH * SAMPLES + BATCH;  // scalar

    dp_fused<<<dim3(BATCH), dim3(256), 0, stream>>>(
        rays_o, rays_d, grid, atoms, rgb, alpha, depth, loss);
}

// Round 4
// 16.530 us; speedup vs baseline: 3.8101x; 1.2371x over previous
//
#include <hip/hip_runtime.h>
#include <math.h>

#define R_ 1.3f
#define NCOARSE 32
#define SAMPLES 383
#define BATCH 512
#define STEPSZ 0.0203125f                  // 2*1.3/32/2/2
#define INV_FINE_VLEN 24.615384615384617f  // 64 / 2.6

using f32x4 = __attribute__((ext_vector_type(4))) float;
using s16x8 = __attribute__((ext_vector_type(8))) short;
using u32x4 = __attribute__((ext_vector_type(4))) unsigned int;

// f32 pair -> packed bf16 (RNE)
__device__ __forceinline__ unsigned int packbf2(float lo, float hi) {
    unsigned int a = __builtin_bit_cast(unsigned int, lo);
    unsigned int b = __builtin_bit_cast(unsigned int, hi);
    a = (a + 0x7fffu + ((a >> 16) & 1u)) >> 16;
    b = (b + 0x7fffu + ((b >> 16) & 1u)) >> 16;
    return (a & 0xffffu) | (b << 16);
}

// Per-dim: summed weight W[t] and coarse index C[t] for fine-parity t.
__device__ __forceinline__ void dimwc(float p, float* W, int* C) {
    float post0 = fminf(fmaxf(floorf(p - 0.5f), 0.f), 63.f);
    float post1 = fminf(fmaxf(floorf(p + 0.5f), 0.f), 63.f);
    float w0 = 1.f - fabsf(p - (post0 + 0.5f));
    float w1 = 1.f - fabsf(p - (post1 + 0.5f));
    int i0 = (int)post0, i1 = (int)post1;
    int f0 = i0 & 1, f1 = i1 & 1;
    W[0] = (f0 == 0 ? w0 : 0.f) + (f1 == 0 ? w1 : 0.f);
    W[1] = (f0 == 1 ? w0 : 0.f) + (f1 == 1 ? w1 : 0.f);
    int c0 = i0 >> 1, c1 = i1 >> 1;
    C[0] = (f0 == 0) ? c0 : c1;
    C[1] = (f0 == 1) ? c0 : c1;
}

// One ray per block, 8 waves. Wave w handles tiles {w, w+8, w+16} but only
// up to ntiles (analytic box-exit bound + guard).
__global__ __launch_bounds__(512, 4) void dp_fused(
    const float* __restrict__ rays_o, const float* __restrict__ rays_d,
    const float* __restrict__ grid, const float* __restrict__ atoms,
    float* __restrict__ out_rgb, float* __restrict__ out_alpha,
    float* __restrict__ out_depth, float* __restrict__ out_loss)
{
    __shared__ u32x4 Bf[16][64];        // 16 KB: B fragments, shared by all waves
    __shared__ u32x4 Abuf[8][256];      // 8 waves x 4 KB: A-frag / D staging
    __shared__ float alpha_l[384];
    __shared__ float sig_l[384][3];

    const int b = blockIdx.x;
    const int tid = threadIdx.x;
    const int wid = tid >> 6, l = tid & 63;
    const int sl = l & 15, fp = l >> 4;
    if (b == 0 && tid == 0) out_loss[0] = 0.f;

    // ---- zero alpha/sig staging ----
    if (tid < 384) alpha_l[tid] = 0.f;
    {
        float* sf = &sig_l[0][0];
        for (int i = tid; i < 384 * 3; i += 512) sf[i] = 0.f;
    }

    // ---- cooperative B-fragment build (once per block) ----
    // slot = kb*128 + nt*64 + l; lane l holds col d = nt*16+(l&15),
    // k = kb*32 + (l>>4)*8 + e (e=0..7 packed as 4 u32 pairs)
    for (int sidx = tid; sidx < 1024; sidx += 512) {
        const int ll = sidx & 63, nt = (sidx >> 6) & 1, kb = sidx >> 7;
        const int a0 = (ll >> 4) * 8, d = nt * 16 + (ll & 15);
        u32x4 o = {0u, 0u, 0u, 0u};
        if (d < 28) {
#pragma unroll
            for (int e2 = 0; e2 < 4; ++e2) {
                const float lo = atoms[(kb * 32 + a0 + 2 * e2) * 28 + d];
                const float hi = atoms[(kb * 32 + a0 + 2 * e2 + 1) * 28 + d];
                o[e2] = packbf2(lo, hi);
            }
        }
        Bf[sidx >> 6][ll] = o;
    }

    // ---- ray setup (block-uniform) ----
    const float ox = rays_o[3 * b], oy = rays_o[3 * b + 1], oz = rays_o[3 * b + 2];
    const float dx = rays_d[3 * b], dy = rays_d[3 * b + 1], dz = rays_d[3 * b + 2];
    const float start = fmaxf(fmaxf(
        fminf((R_ - ox) / dx, (-R_ - ox) / dx),
        fminf((R_ - oy) / dy, (-R_ - oy) / dy)),
        fminf((R_ - oz) / dz, (-R_ - oz) / dz));
    const float t_exit = fminf(fminf(
        fmaxf((R_ - ox) / dx, (-R_ - ox) / dx),
        fmaxf((R_ - oy) / dy, (-R_ - oy) / dy)),
        fmaxf((R_ - oz) / dz, (-R_ - oz) / dz));
    // samples beyond ns are guaranteed outside (>=1-tile overshoot past exit)
    const int ns = (int)floorf((t_exit - start) / STEPSZ) + 2;
    const int ntiles = min(24, (ns >> 4) + 2);

    const float lend = sqrtf(dx * dx + dy * dy + dz * dz);
    const float dist = STEPSZ * lend;
    const float inv = 1.f / lend;
    const float nx = dx * inv, ny = dy * inv, nz = dz * inv;
    float sh[9];
    sh[0] = 0.28209479177387814f;
    sh[1] = -0.48860251190291987f * ny;
    sh[2] = 0.48860251190291987f * nz;
    sh[3] = -0.48860251190291987f * nx;
    sh[4] = 1.0925484305920792f * nx * ny;
    sh[5] = -1.0925484305920792f * ny * nz;
    sh[6] = 0.31539156525252005f * (2.f * nz * nz - nx * nx - ny * ny);
    sh[7] = -1.0925484305920792f * nx * nz;
    sh[8] = 0.5462742152960396f * (nx * nx - ny * ny);

    __syncthreads();   // Bf + zeroed staging visible to all

    u32x4* W4 = &Abuf[wid][0];
    float* Dbuf = (float*)W4;          // stride-33 D staging (2112 B < 4 KB)

    // ---- sample phase ----
    for (int t = wid; t < ntiles; t += 8) {
        const int s = t * 16 + sl;
        const float tt = start + s * STEPSZ;
        const float px = ox + tt * dx, py = oy + tt * dy, pz = oz + tt * dz;
        const bool m = (s < SAMPLES) &&
                       (px > -R_ && px < R_ && py > -R_ && py < R_ && pz > -R_ && pz < R_);
        if (__ballot(m) == 0ull) continue;   // staging pre-zeroed

        float W0[2], W1[2], W2[2];
        int C0[2], C1[2], C2[2];
        dimwc((px + R_) * INV_FINE_VLEN, W0, C0);
        dimwc((py + R_) * INV_FINE_VLEN, W1, C1);
        dimwc((pz + R_) * INV_FINE_VLEN, W2, C2);
        const float msk = m ? 1.f : 0.f;

        f32x4 acc0 = {0.f, 0.f, 0.f, 0.f};
        f32x4 acc1 = {0.f, 0.f, 0.f, 0.f};
        // two stages: stage s builds frags f=4s+fp (4 KB), then 8 MFMAs
#pragma unroll
        for (int stg = 0; stg < 2; ++stg) {
            const int f = 4 * stg + fp;
            const int fx = (f >> 2) & 1, fy = (f >> 1) & 1, fz = f & 1;
            const float wf = msk * W0[fx] * W1[fy] * W2[fz];
            const int cf = (C0[fx] * NCOARSE + C1[fy]) * NCOARSE + C2[fz];
            const f32x4* gr = (const f32x4*)(grid + cf * 32);
#pragma unroll
            for (int g4 = 0; g4 < 4; ++g4) {
                const f32x4 v0 = gr[2 * g4];
                const f32x4 v1 = gr[2 * g4 + 1];
                u32x4 o;
                o.x = packbf2(wf * v0.x, wf * v0.y);
                o.y = packbf2(wf * v0.z, wf * v0.w);
                o.z = packbf2(wf * v1.x, wf * v1.y);
                o.w = packbf2(wf * v1.z, wf * v1.w);
                W4[fp * 64 + 16 * g4 + sl] = o;
            }
#pragma unroll
            for (int kb2 = 0; kb2 < 4; ++kb2) {
                const int kb = 4 * stg + kb2;
                const s16x8 af = __builtin_bit_cast(s16x8, W4[kb2 * 64 + l]);
                acc0 = __builtin_amdgcn_mfma_f32_16x16x32_bf16(
                    af, __builtin_bit_cast(s16x8, Bf[kb * 2 + 0][l]), acc0, 0, 0, 0);
                acc1 = __builtin_amdgcn_mfma_f32_16x16x32_bf16(
                    af, __builtin_bit_cast(s16x8, Bf[kb * 2 + 1][l]), acc1, 0, 0, 0);
            }
        }

        // D -> LDS, row = sample slot, stride 33 (bank-conflict-free reads)
#pragma unroll
        for (int r = 0; r < 4; ++r) {
            Dbuf[(4 * fp + r) * 33 + sl]      = acc0[r];
            Dbuf[(4 * fp + r) * 33 + sl + 16] = acc1[r];
        }

        // epilogue: lane -> (sample s2, channel c)
        const int s2 = l >> 2, c = l & 3;
        const int so = t * 16 + s2;
        if (c == 3) {
            const float sigma = fmaxf(Dbuf[s2 * 33 + 27], 0.f);
            alpha_l[so] = 1.f - expf(-sigma * dist);
        } else {
            float r_ = 0.f;
#pragma unroll
            for (int k = 0; k < 9; ++k) r_ += sh[k] * Dbuf[s2 * 33 + c * 9 + k];
            sig_l[so][c] = 1.f / (1.f + expf(-r_));
        }
    }

    __syncthreads();

    // coalesced alpha store
    if (tid < SAMPLES) out_alpha[b * SAMPLES + tid] = alpha_l[tid];

    // ---- compositing scan (wave 0) ----
    if (wid == 0) {
        float Tacc = 1.f;
        float r0 = 0.f, r1 = 0.f, r2 = 0.f, sd = 0.f, sa = 0.f;
        for (int j = 0; j < 6; ++j) {
            const int s = j * 64 + l;
            const bool v = s < SAMPLES;
            const float a = v ? alpha_l[s] : 0.f;
            float incl = v ? (1.f - a + 1e-10f) : 1.f;
#pragma unroll
            for (int off = 1; off < 64; off <<= 1) {
                const float tm = __shfl_up(incl, off, 64);
                if (l >= off) incl *= tm;
            }
            float excl = __shfl_up(incl, 1, 64);
            if (l == 0) excl = 1.f;
            const float T = Tacc * excl;
            const float al = a * T;
            if (v) {
                r0 += al * sig_l[s][0];
                r1 += al * sig_l[s][1];
                r2 += al * sig_l[s][2];
                sd += al * (start + s * STEPSZ);
                sa += al;
            }
            Tacc *= __shfl(incl, 63, 64);
        }
#pragma unroll
        for (int m = 32; m > 0; m >>= 1) {
            r0 += __shfl_xor(r0, m, 64);
            r1 += __shfl_xor(r1, m, 64);
            r2 += __shfl_xor(r2, m, 64);
            sd += __shfl_xor(sd, m, 64);
            sa += __shfl_xor(sa, m, 64);
        }
        if (l == 0) {
            const float base = 1.f - sa;
            out_rgb[b * 3 + 0] = r0 + base;
            out_rgb[b * 3 + 1] = r1 + base;
            out_rgb[b * 3 + 2] = r2 + base;
            out_depth[b] = sd;
        }
    }
}

extern "C" void kernel_launch(void* const* d_in, const int* in_sizes, int n_in,
                              void* d_out, int out_size, void* d_ws, size_t ws_size,
                              hipStream_t stream) {
    const float* rays_o = (const float*)d_in[0];
    const float* rays_d = (const float*)d_in[1];
    const float* grid   = (const float*)d_in[2];
    const float* atoms  = (const float*)d_in[3];
    float* out   = (float*)d_out;
    float* rgb   = out;                                        // [512,3]
    float* alpha = out + BATCH * 3;                            // [512,383]
    float* depth = out + BATCH * 3 + BATCH * SAMPLES;          // [512]
    float* loss  = out + BATCH * 3 + BATCH * SAMPLES + BATCH;  // scalar

    dp_fused<<<dim3(BATCH), dim3(512), 0, stream>>>(
        rays_o, rays_d, grid, atoms, rgb, alpha, depth, loss);
}